// Round 4
// baseline (2827.282 us; speedup 1.0000x reference)
//
#include <hip/hip_runtime.h>
#include <stdint.h>

typedef unsigned short u16;
typedef __attribute__((ext_vector_type(8))) short bf16x8;
typedef __attribute__((ext_vector_type(4))) short s16x4;
typedef __attribute__((ext_vector_type(4))) float f32x4;

typedef __attribute__((address_space(1))) const uint32_t gas_u32;
typedef __attribute__((address_space(3))) uint32_t las_u32;

__device__ __forceinline__ u16 f2b(float f) {
  union { float f; uint32_t u; } v; v.f = f;
  uint32_t r = v.u + 0x7FFFu + ((v.u >> 16) & 1u);
  return (u16)(r >> 16);
}

__device__ __forceinline__ void gl_lds16(const void* g, void* l) {
  __builtin_amdgcn_global_load_lds((gas_u32*)g, (las_u32*)l, 16, 0, 0);
}

__device__ __forceinline__ void barrier_raw() {
  asm volatile("" ::: "memory");
  __builtin_amdgcn_s_barrier();
  asm volatile("" ::: "memory");
}

#define MM(A_, B_, C_) __builtin_amdgcn_mfma_f32_16x16x32_bf16(A_, B_, C_, 0, 0, 0)

struct GP {
  const u16* A; long long asb;
  const u16* B[3];
  u16* O[3];
  int M, N, K, lda, ldb, ldo;
  float alpha[3];
  int epi[3];            // 0 bf16 | 1 bf16 transposed (vT) | 2 quad | 3 residual | 4 f32-NT
  int nsel;              // QKV fuse: sub-matrix = n0>>10
  int msel;              // ao: B selected by m0>>11
  float* xres;
  const float* lnw;
  float rscale;
  u16* hout;
  float* fout; int ldf;
};

// shared epilogue: MI m-frags x 4 n-frags
template <int MI>
__device__ __forceinline__ void epi_store(const GP& p, int zi, int rbase0, int colb,
                                          const f32x4 (&acc)[MI][4], int l4, int l15) {
  const float alpha = p.alpha[zi];
  const int epi = p.epi[zi];
  u16* __restrict__ Op = p.O[zi];
#pragma unroll
  for (int mi = 0; mi < MI; ++mi) {
    const int rbase = rbase0 + mi * 16 + l4 * 4;
#pragma unroll
    for (int ni = 0; ni < 4; ++ni) {
      const int col = colb + ni * 16 + l15;
      f32x4 v = acc[mi][ni];
      if (epi == 0) {
#pragma unroll
        for (int r = 0; r < 4; ++r)
          Op[(size_t)(rbase + r) * p.ldo + col] = f2b(v[r] * alpha);
      } else if (epi == 1) {
        const int b = rbase >> 11, rb = rbase & 2047;
        s16x4 pk;
#pragma unroll
        for (int r = 0; r < 4; ++r) pk[r] = (short)f2b(v[r] * alpha);
        *(s16x4*)(Op + (size_t)b * 2097152 + (size_t)col * 2048 + rb) = pk;
      } else if (epi == 2) {
#pragma unroll
        for (int r = 0; r < 4; ++r) {
          float y = v[r] * alpha;
          Op[(size_t)(rbase + r) * p.ldo + col] = f2b(y * y * 0.1f + y * 0.1f);
        }
      } else if (epi == 3) {
#pragma unroll
        for (int r = 0; r < 4; ++r) {
          float y = v[r] * alpha;
          size_t ix = (size_t)(rbase + r) * 1024 + col;
          float xn = (p.xres[ix] + y) * p.rscale;
          p.xres[ix] = xn;
          p.hout[ix] = f2b(xn * p.lnw[col] * 0.1f);
        }
      } else {
#pragma unroll
        for (int r = 0; r < 4; ++r)
          __builtin_nontemporal_store(v[r] * alpha, &p.fout[(size_t)(rbase + r) * p.ldf + col]);
      }
    }
  }
}

__device__ __forceinline__ void xcd_swz(int nwg, int orig, int gx, int& bx, int& by) {
  const int xcd = orig & 7, rem = orig >> 3;
  const int qq = nwg >> 3, rr = nwg & 7;
  const int wg = (xcd < rr ? xcd * (qq + 1) : rr * (qq + 1) + (xcd - rr) * qq) + rem;
  bx = wg % gx; by = wg / gx;
}

#define RD_A(off) do { \
  a0 = *(const bf16x8*)(Abase + (off));        a1 = *(const bf16x8*)(Abase + (off) + 1024); \
  a2 = *(const bf16x8*)(Abase + (off) + 2048); a3 = *(const bf16x8*)(Abase + (off) + 3072); \
} while (0)
#define RD_B(off) do { \
  b0 = *(const bf16x8*)(Bbase + (off));        b1 = *(const bf16x8*)(Bbase + (off) + 1024); \
  b2v = *(const bf16x8*)(Bbase + (off) + 2048); b3 = *(const bf16x8*)(Bbase + (off) + 3072); \
} while (0)

#define MF16(R) do { \
  acc[R+0][0]=MM(a0,b0,acc[R+0][0]); acc[R+0][1]=MM(a0,b1,acc[R+0][1]); acc[R+0][2]=MM(a0,b2v,acc[R+0][2]); acc[R+0][3]=MM(a0,b3,acc[R+0][3]); \
  acc[R+1][0]=MM(a1,b0,acc[R+1][0]); acc[R+1][1]=MM(a1,b1,acc[R+1][1]); acc[R+1][2]=MM(a1,b2v,acc[R+1][2]); acc[R+1][3]=MM(a1,b3,acc[R+1][3]); \
  acc[R+2][0]=MM(a2,b0,acc[R+2][0]); acc[R+2][1]=MM(a2,b1,acc[R+2][1]); acc[R+2][2]=MM(a2,b2v,acc[R+2][2]); acc[R+2][3]=MM(a2,b3,acc[R+2][3]); \
  acc[R+3][0]=MM(a3,b0,acc[R+3][0]); acc[R+3][1]=MM(a3,b1,acc[R+3][1]); acc[R+3][2]=MM(a3,b2v,acc[R+3][2]); acc[R+3][3]=MM(a3,b3,acc[R+3][3]); \
} while (0)

// ---------------------------------------------------------------------------
// gemmL: BM=256 BN=128 BK=32, 256 thr = 4 waves (2M x 2N), wave 128x64.
// Triple-buffered LDS 72KB (buf b: A 16KB @ b*24576, B 8KB @ +16384).
// 2 phases/tile (mh0 reads A+B, mh1 reads A, reuses B regs). vmcnt(6)/tile.
// 2 blocks/CU.
// ---------------------------------------------------------------------------
#define L_SA(b, t) do { \
  gl_lds16(gA0 + (size_t)(t) * 32,              lds + (b) * 24576 + wid * 1024); \
  gl_lds16(gA0 + (size_t)(t) * 32 + arow64,     lds + (b) * 24576 + 4096 + wid * 1024); \
  gl_lds16(gA0 + (size_t)(t) * 32 + 2 * arow64, lds + (b) * 24576 + 8192 + wid * 1024); \
  gl_lds16(gA0 + (size_t)(t) * 32 + 3 * arow64, lds + (b) * 24576 + 12288 + wid * 1024); \
} while (0)
#define L_SB(b, t) do { \
  gl_lds16(gB0 + (size_t)(t) * 32,          lds + (b) * 24576 + 16384 + wid * 1024); \
  gl_lds16(gB0 + (size_t)(t) * 32 + brow64, lds + (b) * 24576 + 20480 + wid * 1024); \
} while (0)

__global__ __launch_bounds__(256, 2) void gemmL_k(GP p) {
  extern __shared__ __attribute__((aligned(16))) char lds[];
  const int z = blockIdx.z;
  int bx, by;
  xcd_swz(gridDim.x * gridDim.y, blockIdx.y * gridDim.x + blockIdx.x, gridDim.x, bx, by);
  const int n0 = bx * 128, m0 = by * 256;
  const int zi = p.nsel ? (n0 >> 10) : z;
  const u16* __restrict__ Ap = p.A + (size_t)z * p.asb;
  const u16* __restrict__ Bp = p.B[zi];
  const int nB = p.nsel ? (n0 & 1023) : n0;

  const int tid = threadIdx.x, wid = tid >> 6, lane = tid & 63;
  const int wm = wid >> 1, wn = wid & 1;
  const int l15 = lane & 15, l4 = lane >> 4;
  const int cswz16 = (l4 ^ ((l15 >> 1) & 3)) * 16;

  const f32x4 vzero = {0.f, 0.f, 0.f, 0.f};
  f32x4 acc[8][4];
#pragma unroll
  for (int i = 0; i < 8; ++i)
#pragma unroll
    for (int j = 0; j < 4; ++j) acc[i][j] = vzero;

  const int sr = lane >> 2;
  const int cg8 = ((lane & 3) ^ ((lane >> 3) & 3)) * 8;
  const u16* gA0 = Ap + (size_t)(m0 + wid * 16 + sr) * p.lda + cg8;
  const u16* gB0 = Bp + (size_t)(nB + wid * 16 + sr) * p.ldb + cg8;
  const size_t arow64 = (size_t)64 * p.lda;
  const size_t brow64 = (size_t)64 * p.ldb;

  const int nt = p.K >> 5;   // BK=32

  // prologue: stage tiles 0,1 into bufs 0,1 (nt >= 2 always here)
  L_SA(0, 0); L_SB(0, 0);
  L_SA(1, 1); L_SB(1, 1);
  asm volatile("s_waitcnt vmcnt(6)" ::: "memory");
  barrier_raw();

  bf16x8 a0, a1, a2, a3, b0, b1, b2v, b3;
  int q = 0;
  for (int t = 0; t < nt; ++t) {
    const int bn = (q == 0) ? 2 : q - 1;           // (q+2)%3
    const char* Abase = lds + q * 24576 + (wm * 128 + l15) * 64 + cswz16;
    const char* Bbase = lds + q * 24576 + 16384 + (wn * 64 + l15) * 64 + cswz16;
    // phase 0: mh0 + B
    RD_A(0); RD_B(0);
    if (t + 2 < nt) L_SA(bn, t + 2);
    __builtin_amdgcn_s_setprio(1);
    MF16(0);
    __builtin_amdgcn_s_setprio(0);
    barrier_raw();
    // phase 1: mh1 (B reused in regs)
    RD_A(4096);
    if (t + 2 < nt) L_SB(bn, t + 2);
    __builtin_amdgcn_s_setprio(1);
    MF16(4);
    __builtin_amdgcn_s_setprio(0);
    if (t + 2 < nt) asm volatile("s_waitcnt vmcnt(6)" ::: "memory");
    else            asm volatile("s_waitcnt vmcnt(0)" ::: "memory");
    barrier_raw();
    q = (q == 2) ? 0 : q + 1;
  }

  epi_store<8>(p, zi, m0 + wm * 128, nB + wn * 64, acc, l4, l15);
}

// ---------------------------------------------------------------------------
// gemmS: 128x128, BK=32, 256 thr = 4 waves (2x2), wave 64x64.
// Triple-buffered LDS 48KB (buf b: A 8KB @ b*16384, B 8KB @ +8192).
// 1 phase/tile; vmcnt(4)/tile. 3 blocks/CU.
// ---------------------------------------------------------------------------
#define S_SA(b, t) do { \
  gl_lds16(gA0 + (size_t)(t) * 32,          lds + (b) * 16384 + wid * 1024); \
  gl_lds16(gA0 + (size_t)(t) * 32 + arow64, lds + (b) * 16384 + 4096 + wid * 1024); \
} while (0)
#define S_SB(b, t) do { \
  gl_lds16(gB0 + (size_t)(t) * 32,          lds + (b) * 16384 + 8192 + wid * 1024); \
  gl_lds16(gB0 + (size_t)(t) * 32 + brow64, lds + (b) * 16384 + 12288 + wid * 1024); \
} while (0)

__global__ __launch_bounds__(256, 3) void gemmS_k(GP p) {
  extern __shared__ __attribute__((aligned(16))) char lds[];
  const int z = blockIdx.z;
  int bx, by;
  xcd_swz(gridDim.x * gridDim.y, blockIdx.y * gridDim.x + blockIdx.x, gridDim.x, bx, by);
  const int n0 = bx * 128, m0 = by * 128;
  const int zi = z;
  const u16* __restrict__ Ap = p.A + (size_t)z * p.asb;
  const u16* __restrict__ Bp = p.B[p.msel ? (m0 >> 11) : zi];

  const int tid = threadIdx.x, wid = tid >> 6, lane = tid & 63;
  const int wm = wid >> 1, wn = wid & 1;
  const int l15 = lane & 15, l4 = lane >> 4;
  const int cswz16 = (l4 ^ ((l15 >> 1) & 3)) * 16;

  const f32x4 vzero = {0.f, 0.f, 0.f, 0.f};
  f32x4 acc[4][4];
#pragma unroll
  for (int i = 0; i < 4; ++i)
#pragma unroll
    for (int j = 0; j < 4; ++j) acc[i][j] = vzero;

  const int sr = lane >> 2;
  const int cg8 = ((lane & 3) ^ ((lane >> 3) & 3)) * 8;
  const u16* gA0 = Ap + (size_t)(m0 + wid * 16 + sr) * p.lda + cg8;
  const u16* gB0 = Bp + (size_t)(n0 + wid * 16 + sr) * p.ldb + cg8;
  const size_t arow64 = (size_t)64 * p.lda;
  const size_t brow64 = (size_t)64 * p.ldb;

  const int nt = p.K >> 5;

  S_SA(0, 0); S_SB(0, 0);
  S_SA(1, 1); S_SB(1, 1);
  asm volatile("s_waitcnt vmcnt(4)" ::: "memory");
  barrier_raw();

  bf16x8 a0, a1, a2, a3, b0, b1, b2v, b3;
  int q = 0;
  for (int t = 0; t < nt; ++t) {
    const int bn = (q == 0) ? 2 : q - 1;
    const char* Abase = lds + q * 16384 + (wm * 64 + l15) * 64 + cswz16;
    const char* Bbase = lds + q * 16384 + 8192 + (wn * 64 + l15) * 64 + cswz16;
    RD_A(0); RD_B(0);
    if (t + 2 < nt) { S_SA(bn, t + 2); S_SB(bn, t + 2); }
    __builtin_amdgcn_s_setprio(1);
    MF16(0);
    __builtin_amdgcn_s_setprio(0);
    if (t + 2 < nt) asm volatile("s_waitcnt vmcnt(4)" ::: "memory");
    else            asm volatile("s_waitcnt vmcnt(0)" ::: "memory");
    barrier_raw();
    q = (q == 2) ? 0 : q + 1;
  }

  epi_store<4>(p, zi, m0 + wm * 64, n0 + wn * 64, acc, l4, l15);
}

// ---------------------------------------------------------------------------
__global__ __launch_bounds__(256) void embed_k(const int* __restrict__ idx, const float* __restrict__ wte,
                                               const float* __restrict__ wpe, const float* __restrict__ ln1,
                                               float* __restrict__ x, u16* __restrict__ h) {
  const int bt = blockIdx.x;
  const int t = bt & 2047;
  const int tok = idx[bt];
  const int e = threadIdx.x * 4;
  const float4 wv = *(const float4*)(wte + (size_t)tok * 1024 + e);
  const float4 pv = *(const float4*)(wpe + (size_t)t * 1024 + e);
  const float4 lv = *(const float4*)(ln1 + e);
  float4 xo;
  xo.x = (wv.x + pv.x) * 0.01f;
  xo.y = (wv.y + pv.y) * 0.01f;
  xo.z = (wv.z + pv.z) * 0.01f;
  xo.w = (wv.w + pv.w) * 0.01f;
  *(float4*)(x + (size_t)bt * 1024 + e) = xo;
  s16x4 hv;
  hv[0] = (short)f2b(xo.x * lv.x * 0.1f);
  hv[1] = (short)f2b(xo.y * lv.y * 0.1f);
  hv[2] = (short)f2b(xo.z * lv.z * 0.1f);
  hv[3] = (short)f2b(xo.w * lv.w * 0.1f);
  *(s16x4*)(h + (size_t)bt * 1024 + e) = hv;
}

__global__ __launch_bounds__(256) void cvt_k(const float* __restrict__ src, u16* __restrict__ dst, long long n) {
  long long i = ((long long)blockIdx.x * 256 + threadIdx.x) * 8;
  const long long stride = (long long)gridDim.x * 256 * 8;
  for (; i < n; i += stride) {
    const float4 a = *(const float4*)(src + i);
    const float4 b = *(const float4*)(src + i + 4);
    bf16x8 o;
    o[0] = (short)f2b(a.x); o[1] = (short)f2b(a.y); o[2] = (short)f2b(a.z); o[3] = (short)f2b(a.w);
    o[4] = (short)f2b(b.x); o[5] = (short)f2b(b.y); o[6] = (short)f2b(b.z); o[7] = (short)f2b(b.w);
    *(bf16x8*)(dst + i) = o;
  }
}

__global__ __launch_bounds__(256) void cvt_layer_k(const float* __restrict__ wq, const float* __restrict__ wk,
                                                   const float* __restrict__ wv, const float* __restrict__ wo,
                                                   const float* __restrict__ f1, const float* __restrict__ f2,
                                                   u16* __restrict__ dst) {
  const long long M1 = 1ll << 20;
  long long i = ((long long)blockIdx.x * 256 + threadIdx.x) * 8;
  const float* s; long long off;
  if      (i < M1)     { s = wq; off = i; }
  else if (i < 2 * M1) { s = wk; off = i - M1; }
  else if (i < 3 * M1) { s = wv; off = i - 2 * M1; }
  else if (i < 4 * M1) { s = wo; off = i - 3 * M1; }
  else if (i < 6 * M1) { s = f1; off = i - 4 * M1; }
  else                 { s = f2; off = i - 6 * M1; }
  const float4 a = *(const float4*)(s + off);
  const float4 b = *(const float4*)(s + off + 4);
  bf16x8 o;
  o[0] = (short)f2b(a.x); o[1] = (short)f2b(a.y); o[2] = (short)f2b(a.z); o[3] = (short)f2b(a.w);
  o[4] = (short)f2b(b.x); o[5] = (short)f2b(b.y); o[6] = (short)f2b(b.z); o[7] = (short)f2b(b.w);
  *(bf16x8*)(dst + i) = o;
}

// ---------------------------------------------------------------------------
extern "C" void kernel_launch(void* const* d_in, const int* in_sizes, int n_in,
                              void* d_out, int out_size, void* d_ws, size_t ws_size,
                              hipStream_t stream) {
  const int*   idx  = (const int*)  d_in[0];
  const float* wte  = (const float*)d_in[1];
  const float* wpe  = (const float*)d_in[2];
  const float* ln1w = (const float*)d_in[3];
  const float* Wq   = (const float*)d_in[4];
  const float* Wk   = (const float*)d_in[5];
  const float* Wv   = (const float*)d_in[6];
  const float* Wo   = (const float*)d_in[7];
  const float* ln2w = (const float*)d_in[8];
  const float* fc1  = (const float*)d_in[9];
  const float* fc2  = (const float*)d_in[10];
  const float* lnfw = (const float*)d_in[11];
  const float* lmh  = (const float*)d_in[12];
  float* out = (float*)d_out;

  char* w = (char*)d_ws;
  float* x  = (float*)w;  w += (size_t)4096 * 1024 * 4;
  u16* h    = (u16*)w;    w += (size_t)4096 * 1024 * 2;
  u16* q    = (u16*)w;    w += (size_t)4096 * 1024 * 2;
  u16* kb   = (u16*)w;    w += (size_t)4096 * 1024 * 2;
  u16* vT   = (u16*)w;    w += (size_t)2 * 1024 * 2048 * 2;
  u16* a    = (u16*)w;    w += (size_t)2 * 2048 * 2048 * 2;
  u16* ao   = (u16*)w;    w += (size_t)4096 * 1024 * 2;
  u16* mb   = (u16*)w;    w += (size_t)4096 * 2048 * 2;
  u16* lw   = (u16*)w;    w += (size_t)8 * 1024 * 1024 * 2;
  u16* lmhb = q;

  const size_t SHL = 73728, SHS = 49152;

  embed_k<<<4096, 256, 0, stream>>>(idx, wte, wpe, ln1w, x, h);

  for (int l = 0; l < 12; ++l) {
    cvt_layer_k<<<4096, 256, 0, stream>>>(Wq + (size_t)l * 1048576, Wk + (size_t)l * 1048576,
                                          Wv + (size_t)l * 1048576, Wo + (size_t)l * 1048576,
                                          fc1 + (size_t)l * 2097152, fc2 + (size_t)l * 2097152, lw);
    { // QKV fused: N=3072, n-tile selects weight/alpha/epi/output; v transposed
      GP p{};
      p.A = h; p.asb = 0;
      p.B[0] = lw; p.B[1] = lw + 1048576; p.B[2] = lw + 2097152;
      p.O[0] = q; p.O[1] = kb; p.O[2] = vT;
      p.M = 4096; p.N = 3072; p.K = 1024; p.lda = 1024; p.ldb = 1024; p.ldo = 1024;
      p.alpha[0] = 0.01f; p.alpha[1] = 0.01f; p.alpha[2] = 0.1f;
      p.epi[0] = 0; p.epi[1] = 0; p.epi[2] = 1;
      p.nsel = 1;
      gemmL_k<<<dim3(24, 16, 1), 256, SHL, stream>>>(p);
    }
    { // a = quad(q @ k^T * 0.01) per batch
      GP p{};
      p.A = q; p.asb = 2097152;
      p.B[0] = kb; p.B[1] = kb + 2097152;
      p.O[0] = a; p.O[1] = a + 4194304;
      p.M = 2048; p.N = 2048; p.K = 1024; p.lda = 1024; p.ldb = 1024; p.ldo = 2048;
      p.alpha[0] = p.alpha[1] = 0.01f; p.epi[0] = p.epi[1] = 2;
      gemmL_k<<<dim3(16, 8, 2), 256, SHL, stream>>>(p);
    }
    { // ao = a @ v * 0.01 (M batch-fused; B selected by m0)
      GP p{};
      p.A = a; p.asb = 0;
      p.B[0] = vT; p.B[1] = vT + 2097152;
      p.O[0] = ao;
      p.M = 4096; p.N = 1024; p.K = 2048; p.lda = 2048; p.ldb = 2048; p.ldo = 1024;
      p.alpha[0] = 0.01f; p.epi[0] = 0;
      p.msel = 1;
      gemmS_k<<<dim3(8, 32, 1), 256, SHS, stream>>>(p);
    }
    { // x = (x + ao@Wo^T*0.1)*0.05 ; h = x*ln2*0.1
      GP p{};
      p.A = ao; p.asb = 0; p.B[0] = lw + 3145728;
      p.M = 4096; p.N = 1024; p.K = 1024; p.lda = 1024; p.ldb = 1024; p.ldo = 1024;
      p.alpha[0] = 0.1f; p.epi[0] = 3;
      p.xres = x; p.lnw = ln2w + (size_t)l * 1024; p.rscale = 0.05f; p.hout = h;
      gemmS_k<<<dim3(8, 32, 1), 256, SHS, stream>>>(p);
    }
    { // m = quad(h @ fc1^T * 0.05)
      GP p{};
      p.A = h; p.asb = 0; p.B[0] = lw + 4194304; p.O[0] = mb;
      p.M = 4096; p.N = 2048; p.K = 1024; p.lda = 1024; p.ldb = 1024; p.ldo = 2048;
      p.alpha[0] = 0.05f; p.epi[0] = 2;
      gemmL_k<<<dim3(16, 16, 1), 256, SHL, stream>>>(p);
    }
    { // x = (x + m@fc2^T*0.05)*0.05*s ; h = x*ln_next*0.1
      GP p{};
      p.A = mb; p.asb = 0; p.B[0] = lw + 6291456;
      p.M = 4096; p.N = 1024; p.K = 2048; p.lda = 2048; p.ldb = 2048; p.ldo = 1024;
      p.alpha[0] = 0.05f; p.epi[0] = 3;
      p.xres = x;
      p.rscale = (l < 11) ? 0.005f : 0.05f;
      p.lnw = (l < 11) ? (ln1w + (size_t)(l + 1) * 1024) : lnfw;
      p.hout = h;
      gemmS_k<<<dim3(8, 32, 1), 256, SHS, stream>>>(p);
    }
  }

  cvt_k<<<2048, 256, 0, stream>>>(lmh, lmhb, 32768000ll);
  { // logits = h @ lm_head^T * 0.5 (f32, nontemporal)
    GP p{};
    p.A = h; p.asb = 0; p.B[0] = lmhb;
    p.M = 4096; p.N = 32000; p.K = 1024; p.lda = 1024; p.ldb = 1024; p.ldo = 0;
    p.alpha[0] = 0.5f; p.epi[0] = 4;
    p.fout = out; p.ldf = 32000;
    gemmL_k<<<dim3(250, 16, 1), 256, SHL, stream>>>(p);
  }
}

// Round 5
// 2589.097 us; speedup vs baseline: 1.0920x; 1.0920x over previous
//
#include <hip/hip_runtime.h>
#include <stdint.h>

typedef unsigned short u16;
typedef __attribute__((ext_vector_type(8))) short bf16x8;
typedef __attribute__((ext_vector_type(4))) short s16x4;
typedef __attribute__((ext_vector_type(4))) float f32x4;

typedef __attribute__((address_space(1))) const uint32_t gas_u32;
typedef __attribute__((address_space(3))) uint32_t las_u32;

__device__ __forceinline__ u16 f2b(float f) {
  union { float f; uint32_t u; } v; v.f = f;
  uint32_t r = v.u + 0x7FFFu + ((v.u >> 16) & 1u);
  return (u16)(r >> 16);
}

__device__ __forceinline__ void gl_lds16(const void* g, void* l) {
  __builtin_amdgcn_global_load_lds((gas_u32*)g, (las_u32*)l, 16, 0, 0);
}

__device__ __forceinline__ void barrier_raw() {
  asm volatile("" ::: "memory");
  __builtin_amdgcn_s_barrier();
  asm volatile("" ::: "memory");
}

#define MM(A_, B_, C_) __builtin_amdgcn_mfma_f32_16x16x32_bf16(A_, B_, C_, 0, 0, 0)

struct GP {
  const u16* A; long long asb;
  const u16* B[3]; long long bsb;
  u16* O[3]; long long osb;
  int M, N, K, lda, ldb, ldo;
  float alpha[3];
  int epi[3];            // 0 bf16 | 1 bf16 transposed | 2 quad | 3 residual | 4 f32
  int nsel;              // QKV fuse: select by n0>>10
  int msel;              // batched-B by m0>>11 (B = B[zi] + (m0>>11)*bsb)
  float* xres;
  const float* lnw;
  float rscale;
  u16* hout;
  float* fout; int ldf;
};

template <int MI>
__device__ __forceinline__ void epi_store(const GP& p, u16* __restrict__ Op, float alpha, int epi,
                                          int rbase0, int colb, const f32x4 (&acc)[MI][4], int l4, int l15) {
#pragma unroll
  for (int mi = 0; mi < MI; ++mi) {
    const int rbase = rbase0 + mi * 16 + l4 * 4;
#pragma unroll
    for (int ni = 0; ni < 4; ++ni) {
      const int col = colb + ni * 16 + l15;
      f32x4 v = acc[mi][ni];
      if (epi == 0) {
#pragma unroll
        for (int r = 0; r < 4; ++r)
          Op[(size_t)(rbase + r) * p.ldo + col] = f2b(v[r] * alpha);
      } else if (epi == 1) {
        const int b = rbase >> 11, rb = rbase & 2047;
        s16x4 pk;
#pragma unroll
        for (int r = 0; r < 4; ++r) pk[r] = (short)f2b(v[r] * alpha);
        *(s16x4*)(Op + (size_t)b * 2097152 + (size_t)col * 2048 + rb) = pk;
      } else if (epi == 2) {
#pragma unroll
        for (int r = 0; r < 4; ++r) {
          float y = v[r] * alpha;
          Op[(size_t)(rbase + r) * p.ldo + col] = f2b(y * y * 0.1f + y * 0.1f);
        }
      } else if (epi == 3) {
#pragma unroll
        for (int r = 0; r < 4; ++r) {
          float y = v[r] * alpha;
          size_t ix = (size_t)(rbase + r) * 1024 + col;
          float xn = (p.xres[ix] + y) * p.rscale;
          p.xres[ix] = xn;
          p.hout[ix] = f2b(xn * p.lnw[col] * 0.1f);
        }
      } else {
#pragma unroll
        for (int r = 0; r < 4; ++r)
          p.fout[(size_t)(rbase + r) * p.ldf + col] = v[r] * alpha;
      }
    }
  }
}

__device__ __forceinline__ void xcd_swz(int nwg, int orig, int gx, int& bx, int& by) {
  const int xcd = orig & 7, rem = orig >> 3;
  const int qq = nwg >> 3, rr = nwg & 7;
  const int wg = (xcd < rr ? xcd * (qq + 1) : rr * (qq + 1) + (xcd - rr) * qq) + rem;
  bx = wg % gx; by = wg / gx;
}

#define RD_A(off) do { \
  a0 = *(const bf16x8*)(Abase + (off));        a1 = *(const bf16x8*)(Abase + (off) + 1024); \
  a2 = *(const bf16x8*)(Abase + (off) + 2048); a3 = *(const bf16x8*)(Abase + (off) + 3072); \
} while (0)
#define RD_B(off) do { \
  b0 = *(const bf16x8*)(Bbase + (off));        b1 = *(const bf16x8*)(Bbase + (off) + 1024); \
  b2 = *(const bf16x8*)(Bbase + (off) + 2048); b3 = *(const bf16x8*)(Bbase + (off) + 3072); \
} while (0)

#define MF16(R) do { \
  acc[R+0][0]=MM(a0,b0,acc[R+0][0]); acc[R+0][1]=MM(a0,b1,acc[R+0][1]); acc[R+0][2]=MM(a0,b2,acc[R+0][2]); acc[R+0][3]=MM(a0,b3,acc[R+0][3]); \
  acc[R+1][0]=MM(a1,b0,acc[R+1][0]); acc[R+1][1]=MM(a1,b1,acc[R+1][1]); acc[R+1][2]=MM(a1,b2,acc[R+1][2]); acc[R+1][3]=MM(a1,b3,acc[R+1][3]); \
  acc[R+2][0]=MM(a2,b0,acc[R+2][0]); acc[R+2][1]=MM(a2,b1,acc[R+2][1]); acc[R+2][2]=MM(a2,b2,acc[R+2][2]); acc[R+2][3]=MM(a2,b3,acc[R+2][3]); \
  acc[R+3][0]=MM(a3,b0,acc[R+3][0]); acc[R+3][1]=MM(a3,b1,acc[R+3][1]); acc[R+3][2]=MM(a3,b2,acc[R+3][2]); acc[R+3][3]=MM(a3,b3,acc[R+3][3]); \
} while (0)

#define PHASE_MID() do { \
  barrier_raw(); \
  asm volatile("s_waitcnt lgkmcnt(0)" ::: "memory"); \
  __builtin_amdgcn_sched_barrier(0); \
  __builtin_amdgcn_s_setprio(1); \
} while (0)
#define PHASE_END() do { \
  __builtin_amdgcn_s_setprio(0); \
  __builtin_amdgcn_sched_barrier(0); \
  barrier_raw(); \
} while (0)

// ---------------------------------------------------------------------------
// gemmL: 256x256, BK=64, 512 thr = 8 waves (2M x 4N), wave 128x64.
// 4 phases/K-tile with B-register reuse across m-halves; dbuf 128KB; vmcnt(6).
// m-fastest block mapping: bx -> m-tile, by -> n-tile.
// ---------------------------------------------------------------------------
#define LSA(q, kh, t) do { \
  gl_lds16(gA0 + (size_t)(t) * 64 + (kh) * 32, lAw + (q) * 65536 + (kh) * 16384); \
  gl_lds16(gA1 + (size_t)(t) * 64 + (kh) * 32, lAw + (q) * 65536 + (kh) * 16384 + 8192); \
} while (0)
#define LSB(q, kh, t) do { \
  gl_lds16(gB0 + (size_t)(t) * 64 + (kh) * 32, lBw + (q) * 65536 + (kh) * 16384); \
  gl_lds16(gB1 + (size_t)(t) * 64 + (kh) * 32, lBw + (q) * 65536 + (kh) * 16384 + 8192); \
} while (0)

__global__ __launch_bounds__(512, 2) void gemmL_k(GP p) {
  extern __shared__ __attribute__((aligned(16))) char lds[];
  const int z = blockIdx.z;
  int bx, by;
  xcd_swz(gridDim.x * gridDim.y, blockIdx.y * gridDim.x + blockIdx.x, gridDim.x, bx, by);
  const int m0 = bx * 256, n0 = by * 256;
  const int zi = p.nsel ? (n0 >> 10) : 0;
  const int nB = p.nsel ? (n0 & 1023) : n0;
  const u16* __restrict__ Ap = p.A + (size_t)z * p.asb;
  const u16* __restrict__ Bp = p.B[zi] + (size_t)(p.msel ? (m0 >> 11) : z) * p.bsb;

  const int tid = threadIdx.x, wid = tid >> 6, lane = tid & 63;
  const int wm = wid >> 2, wn = wid & 3;
  const int l15 = lane & 15, l4 = lane >> 4;
  const int cswz16 = (l4 ^ ((l15 >> 1) & 3)) * 16;

  const f32x4 vzero = {0.f, 0.f, 0.f, 0.f};
  f32x4 acc[8][4];
#pragma unroll
  for (int i = 0; i < 8; ++i)
#pragma unroll
    for (int j = 0; j < 4; ++j) acc[i][j] = vzero;

  const int sr = lane >> 2;
  const int cg8 = ((lane & 3) ^ ((lane >> 3) & 3)) * 8;
  const u16* gA0 = Ap + (size_t)(m0 + wid * 16 + sr) * p.lda + cg8;
  const u16* gA1 = gA0 + (size_t)128 * p.lda;
  const u16* gB0 = Bp + (size_t)(nB + wid * 16 + sr) * p.ldb + cg8;
  const u16* gB1 = gB0 + (size_t)128 * p.ldb;
  char* lAw = lds + wid * 1024;
  char* lBw = lds + 32768 + wid * 1024;

  const int nt = p.K >> 6;

  LSB(0, 0, 0); LSA(0, 0, 0); LSB(0, 1, 0); LSA(0, 1, 0);
  if (nt > 1) {
    LSB(1, 0, 1); LSA(1, 0, 1); LSB(1, 1, 1);
    asm volatile("s_waitcnt vmcnt(6)" ::: "memory");
  } else {
    asm volatile("s_waitcnt vmcnt(0)" ::: "memory");
  }
  barrier_raw();

  bf16x8 a0, a1, a2, a3, b0, b1, b2, b3;
  for (int t = 0; t < nt; ++t) {
    const int q = t & 1;
    const char* Abase = lds + q * 65536 + (wm * 128 + l15) * 64 + cswz16;
    const char* Bbase = lds + q * 65536 + 32768 + (wn * 64 + l15) * 64 + cswz16;
    // phi0: kh0, mh0 (reads A mh0 + B)
    RD_A(0); RD_B(0);
    if (t + 1 < nt) LSA(q ^ 1, 1, t + 1);
    PHASE_MID(); MF16(0); PHASE_END();
    // phi1: kh0, mh1 (A only; B reused)
    RD_A(4096);
    if (t + 2 < nt) LSB(q, 0, t + 2);
    PHASE_MID(); MF16(4); PHASE_END();
    // phi2: kh1, mh0
    RD_A(16384); RD_B(16384);
    if (t + 2 < nt) LSA(q, 0, t + 2);
    PHASE_MID(); MF16(0); PHASE_END();
    // phi3: kh1, mh1
    RD_A(16384 + 4096);
    if (t + 2 < nt) LSB(q, 1, t + 2);
    PHASE_MID(); MF16(4);
    __builtin_amdgcn_s_setprio(0);
    __builtin_amdgcn_sched_barrier(0);
    if (t + 2 < nt) asm volatile("s_waitcnt vmcnt(6)" ::: "memory");
    else            asm volatile("s_waitcnt vmcnt(0)" ::: "memory");
    barrier_raw();
  }

  u16* Op = p.O[zi] + (size_t)z * p.osb;
  epi_store<8>(p, Op, p.alpha[zi], p.epi[zi], m0 + wm * 128, nB + wn * 64, acc, l4, l15);
}

// ---------------------------------------------------------------------------
// gemmS: 128x128, BK=64, 256 thr = 4 waves (2x2), wave 64x64, dbuf 64KB,
// 2 phases/tile, vmcnt(4). m-fastest mapping.
// ---------------------------------------------------------------------------
#define SSA(q, kh, t) do { \
  gl_lds16(gA0 + (size_t)(t) * 64 + (kh) * 32, lAw + (q) * 32768 + (kh) * 8192); \
  gl_lds16(gA1 + (size_t)(t) * 64 + (kh) * 32, lAw + (q) * 32768 + (kh) * 8192 + 4096); \
} while (0)
#define SSB(q, kh, t) do { \
  gl_lds16(gB0 + (size_t)(t) * 64 + (kh) * 32, lBw + (q) * 32768 + (kh) * 8192); \
  gl_lds16(gB1 + (size_t)(t) * 64 + (kh) * 32, lBw + (q) * 32768 + (kh) * 8192 + 4096); \
} while (0)

__global__ __launch_bounds__(256, 2) void gemmS_k(GP p) {
  extern __shared__ __attribute__((aligned(16))) char lds[];
  const int z = blockIdx.z;
  int bx, by;
  xcd_swz(gridDim.x * gridDim.y, blockIdx.y * gridDim.x + blockIdx.x, gridDim.x, bx, by);
  const int m0 = bx * 128, n0 = by * 128;
  const u16* __restrict__ Ap = p.A + (size_t)z * p.asb;
  const u16* __restrict__ Bp = p.B[0] + (size_t)(p.msel ? (m0 >> 11) : z) * p.bsb;

  const int tid = threadIdx.x, wid = tid >> 6, lane = tid & 63;
  const int wm = wid >> 1, wn = wid & 1;
  const int l15 = lane & 15, l4 = lane >> 4;
  const int cswz16 = (l4 ^ ((l15 >> 1) & 3)) * 16;

  const f32x4 vzero = {0.f, 0.f, 0.f, 0.f};
  f32x4 acc[4][4];
#pragma unroll
  for (int i = 0; i < 4; ++i)
#pragma unroll
    for (int j = 0; j < 4; ++j) acc[i][j] = vzero;

  const int sr = lane >> 2;
  const int cg8 = ((lane & 3) ^ ((lane >> 3) & 3)) * 8;
  const u16* gA0 = Ap + (size_t)(m0 + wid * 16 + sr) * p.lda + cg8;
  const u16* gA1 = gA0 + (size_t)64 * p.lda;
  const u16* gB0 = Bp + (size_t)(n0 + wid * 16 + sr) * p.ldb + cg8;
  const u16* gB1 = gB0 + (size_t)64 * p.ldb;
  char* lAw = lds + wid * 1024;
  char* lBw = lds + 16384 + wid * 1024;

  const int nt = p.K >> 6;

  SSA(0, 0, 0); SSB(0, 0, 0); SSA(0, 1, 0); SSB(0, 1, 0);
  if (nt > 1) {
    SSA(1, 0, 1); SSB(1, 0, 1);
    asm volatile("s_waitcnt vmcnt(4)" ::: "memory");
  } else {
    asm volatile("s_waitcnt vmcnt(0)" ::: "memory");
  }
  barrier_raw();

  bf16x8 a0, a1, a2, a3, b0, b1, b2, b3;
  for (int t = 0; t < nt; ++t) {
    const int q = t & 1;
    const char* Abase = lds + q * 32768 + (wm * 64 + l15) * 64 + cswz16;
    const char* Bbase = lds + q * 32768 + 16384 + (wn * 64 + l15) * 64 + cswz16;
    // phi0: kh0
    RD_A(0); RD_B(0);
    if (t + 1 < nt) { SSA(q ^ 1, 1, t + 1); SSB(q ^ 1, 1, t + 1); }
    PHASE_MID(); MF16(0); PHASE_END();
    // phi1: kh1
    RD_A(8192); RD_B(8192);
    if (t + 2 < nt) { SSA(q, 0, t + 2); SSB(q, 0, t + 2); }
    PHASE_MID(); MF16(0);
    __builtin_amdgcn_s_setprio(0);
    __builtin_amdgcn_sched_barrier(0);
    if (t + 2 < nt) asm volatile("s_waitcnt vmcnt(4)" ::: "memory");
    else            asm volatile("s_waitcnt vmcnt(0)" ::: "memory");
    barrier_raw();
  }

  u16* Op = p.O[0] + (size_t)z * p.osb;
  epi_store<4>(p, Op, p.alpha[0], p.epi[0], m0 + wm * 64, n0 + wn * 64, acc, l4, l15);
}

// ---------------------------------------------------------------------------
__global__ __launch_bounds__(256) void embed_k(const int* __restrict__ idx, const float* __restrict__ wte,
                                               const float* __restrict__ wpe, const float* __restrict__ ln1,
                                               float* __restrict__ x, u16* __restrict__ h) {
  const int bt = blockIdx.x;
  const int t = bt & 2047;
  const int tok = idx[bt];
  const int e = threadIdx.x * 4;
  const float4 wv = *(const float4*)(wte + (size_t)tok * 1024 + e);
  const float4 pv = *(const float4*)(wpe + (size_t)t * 1024 + e);
  const float4 lv = *(const float4*)(ln1 + e);
  float4 xo;
  xo.x = (wv.x + pv.x) * 0.01f;
  xo.y = (wv.y + pv.y) * 0.01f;
  xo.z = (wv.z + pv.z) * 0.01f;
  xo.w = (wv.w + pv.w) * 0.01f;
  *(float4*)(x + (size_t)bt * 1024 + e) = xo;
  s16x4 hv;
  hv[0] = (short)f2b(xo.x * lv.x * 0.1f);
  hv[1] = (short)f2b(xo.y * lv.y * 0.1f);
  hv[2] = (short)f2b(xo.z * lv.z * 0.1f);
  hv[3] = (short)f2b(xo.w * lv.w * 0.1f);
  *(s16x4*)(h + (size_t)bt * 1024 + e) = hv;
}

__global__ __launch_bounds__(256) void cvt_k(const float* __restrict__ src, u16* __restrict__ dst, long long n) {
  long long i = ((long long)blockIdx.x * 256 + threadIdx.x) * 8;
  const long long stride = (long long)gridDim.x * 256 * 8;
  for (; i < n; i += stride) {
    const float4 a = *(const float4*)(src + i);
    const float4 b = *(const float4*)(src + i + 4);
    bf16x8 o;
    o[0] = (short)f2b(a.x); o[1] = (short)f2b(a.y); o[2] = (short)f2b(a.z); o[3] = (short)f2b(a.w);
    o[4] = (short)f2b(b.x); o[5] = (short)f2b(b.y); o[6] = (short)f2b(b.z); o[7] = (short)f2b(b.w);
    *(bf16x8*)(dst + i) = o;
  }
}

// old full-layer cvt (fallback path): [q 1M][k 1M][v 1M][o 1M][f1 2M][f2 2M]
__global__ __launch_bounds__(256) void cvt_layer_k(const float* __restrict__ wq, const float* __restrict__ wk,
                                                   const float* __restrict__ wv, const float* __restrict__ wo,
                                                   const float* __restrict__ f1, const float* __restrict__ f2,
                                                   u16* __restrict__ dst) {
  const long long M1 = 1ll << 20;
  long long i = ((long long)blockIdx.x * 256 + threadIdx.x) * 8;
  const float* s; long long off;
  if      (i < M1)     { s = wq; off = i; }
  else if (i < 2 * M1) { s = wk; off = i - M1; }
  else if (i < 3 * M1) { s = wv; off = i - 2 * M1; }
  else if (i < 4 * M1) { s = wo; off = i - 3 * M1; }
  else if (i < 6 * M1) { s = f1; off = i - 4 * M1; }
  else                 { s = f2; off = i - 6 * M1; }
  const float4 a = *(const float4*)(s + off);
  const float4 b = *(const float4*)(s + off + 4);
  bf16x8 o;
  o[0] = (short)f2b(a.x); o[1] = (short)f2b(a.y); o[2] = (short)f2b(a.z); o[3] = (short)f2b(a.w);
  o[4] = (short)f2b(b.x); o[5] = (short)f2b(b.y); o[6] = (short)f2b(b.z); o[7] = (short)f2b(b.w);
  *(bf16x8*)(dst + i) = o;
}

// slim per-layer cvt (fused path): [q 1M][k 1M][f1 2M][f2 2M]
__global__ __launch_bounds__(256) void cvt_layer4_k(const float* __restrict__ wq, const float* __restrict__ wk,
                                                    const float* __restrict__ f1, const float* __restrict__ f2,
                                                    u16* __restrict__ dst) {
  const long long M1 = 1ll << 20;
  long long i = ((long long)blockIdx.x * 256 + threadIdx.x) * 8;   // grid 3072 = 6M elems
  const float* s; long long off;
  if      (i < M1)     { s = wq; off = i; }
  else if (i < 2 * M1) { s = wk; off = i - M1; }
  else if (i < 4 * M1) { s = f1; off = i - 2 * M1; }
  else                 { s = f2; off = i - 4 * M1; }
  const float4 a = *(const float4*)(s + off);
  const float4 b = *(const float4*)(s + off + 4);
  bf16x8 o;
  o[0] = (short)f2b(a.x); o[1] = (short)f2b(a.y); o[2] = (short)f2b(a.z); o[3] = (short)f2b(a.w);
  o[4] = (short)f2b(b.x); o[5] = (short)f2b(b.y); o[6] = (short)f2b(b.z); o[7] = (short)f2b(b.w);
  *(bf16x8*)(dst + i) = o;
}

// transpose+convert: WvT[z][e][f] = bf16(Wv[z][f][e]); 64x64 tiles
__global__ __launch_bounds__(256) void cvtT_k(const float* __restrict__ src, u16* __restrict__ dst) {
  __shared__ float tl[64][68];
  const int z = blockIdx.z;
  const int c0 = blockIdx.x * 64, r0 = blockIdx.y * 64;
  const int tid = threadIdx.x;
  const float* s = src + (size_t)z * 1048576;
#pragma unroll
  for (int it = 0; it < 4; ++it) {
    const int r = it * 16 + (tid >> 4);
    const int c4 = (tid & 15) * 4;
    const float4 v = *(const float4*)(s + (size_t)(r0 + r) * 1024 + c0 + c4);
    tl[r][c4] = v.x; tl[r][c4 + 1] = v.y; tl[r][c4 + 2] = v.z; tl[r][c4 + 3] = v.w;
  }
  __syncthreads();
  const int c = tid >> 2;
  const int rr = (tid & 3) * 16;
  u16* d = dst + (size_t)z * 1048576 + (size_t)(c0 + c) * 1024 + r0 + rr;
  bf16x8 o0, o1;
#pragma unroll
  for (int j = 0; j < 8; ++j) o0[j] = (short)f2b(tl[rr + j][c]);
#pragma unroll
  for (int j = 0; j < 8; ++j) o1[j] = (short)f2b(tl[rr + 8 + j][c]);
  *(bf16x8*)d = o0;
  *(bf16x8*)(d + 8) = o1;
}

// ---------------------------------------------------------------------------
extern "C" void kernel_launch(void* const* d_in, const int* in_sizes, int n_in,
                              void* d_out, int out_size, void* d_ws, size_t ws_size,
                              hipStream_t stream) {
  const int*   idx  = (const int*)  d_in[0];
  const float* wte  = (const float*)d_in[1];
  const float* wpe  = (const float*)d_in[2];
  const float* ln1w = (const float*)d_in[3];
  const float* Wq   = (const float*)d_in[4];
  const float* Wk   = (const float*)d_in[5];
  const float* Wv   = (const float*)d_in[6];
  const float* Wo   = (const float*)d_in[7];
  const float* ln2w = (const float*)d_in[8];
  const float* fc1  = (const float*)d_in[9];
  const float* fc2  = (const float*)d_in[10];
  const float* lnfw = (const float*)d_in[11];
  const float* lmh  = (const float*)d_in[12];
  float* out = (float*)d_out;

  char* w = (char*)d_ws;
  float* x  = (float*)w;  w += (size_t)4096 * 1024 * 4;     // 16MB
  u16* h    = (u16*)w;    w += (size_t)4096 * 1024 * 2;     // 8MB
  u16* q    = (u16*)w;    w += (size_t)4096 * 1024 * 2;     // 8MB
  u16* kb   = (u16*)w;    w += (size_t)4096 * 1024 * 2;     // 8MB
  u16* uT   = (u16*)w;    w += (size_t)2 * 1024 * 2048 * 2; // 8MB (u or v, transposed)
  u16* a    = (u16*)w;    w += (size_t)2 * 2048 * 2048 * 2; // 16MB
  u16* mb   = (u16*)w;    w += (size_t)4096 * 2048 * 2;     // 16MB
  u16* lw   = (u16*)w;    w += (size_t)8 * 1024 * 1024 * 2; // 16MB
  u16* WvT  = (u16*)w;    w += (size_t)12 * 1048576 * 2;    // 24MB (fused only)
  u16* WoB  = (u16*)w;    w += (size_t)12 * 1048576 * 2;    // 24MB
  u16* Wvo  = (u16*)w;    w += (size_t)12 * 1048576 * 2;    // 24MB
  u16* lmhb = q;            // 64MB alias over q..mb(+lw tail), all dead at lm_head
  u16* ao   = mb;           // fallback only: dead before fc1 writes mb

  const int fused = (ws_size >= (size_t)(w - (char*)d_ws));
  const size_t SHL = 131072, SHS = 65536;

  embed_k<<<4096, 256, 0, stream>>>(idx, wte, wpe, ln1w, x, h);

  if (fused) {  // precompute Wvo[l] = Wo[l] @ Wv[l]  (C=A@B^T with A=Wo, B=Wv^T)
    cvtT_k<<<dim3(16, 16, 12), 256, 0, stream>>>(Wv, WvT);
    cvt_k<<<2048, 256, 0, stream>>>(Wo, WoB, 12ll * 1048576);
    GP p{};
    p.A = WoB; p.asb = 1048576;
    p.B[0] = WvT; p.bsb = 1048576;
    p.O[0] = Wvo; p.osb = 1048576;
    p.M = 1024; p.N = 1024; p.K = 1024; p.lda = 1024; p.ldb = 1024; p.ldo = 1024;
    p.alpha[0] = 1.0f; p.epi[0] = 0;
    gemmS_k<<<dim3(8, 8, 12), 256, SHS, stream>>>(p);
  }

  for (int l = 0; l < 12; ++l) {
    if (fused) {
      cvt_layer4_k<<<3072, 256, 0, stream>>>(Wq + (size_t)l * 1048576, Wk + (size_t)l * 1048576,
                                             fc1 + (size_t)l * 2097152, fc2 + (size_t)l * 2097152, lw);
    } else {
      cvt_layer_k<<<4096, 256, 0, stream>>>(Wq + (size_t)l * 1048576, Wk + (size_t)l * 1048576,
                                            Wv + (size_t)l * 1048576, Wo + (size_t)l * 1048576,
                                            fc1 + (size_t)l * 2097152, fc2 + (size_t)l * 2097152, lw);
    }
    { // QKV/QKU fused over N=3072: q, k, and u (=v@Wo^T, fused) or v; 3rd stored transposed
      GP p{};
      p.A = h; p.asb = 0;
      p.B[0] = lw; p.B[1] = lw + 1048576;
      p.B[2] = fused ? (Wvo + (size_t)l * 1048576) : (lw + 2097152);
      p.O[0] = q; p.O[1] = kb; p.O[2] = uT;
      p.M = 4096; p.N = 3072; p.K = 1024; p.lda = 1024; p.ldb = 1024; p.ldo = 1024;
      p.alpha[0] = 0.01f; p.alpha[1] = 0.01f; p.alpha[2] = 0.1f;
      p.epi[0] = 0; p.epi[1] = 0; p.epi[2] = 1;
      p.nsel = 1;
      gemmL_k<<<dim3(16, 12, 1), 512, SHL, stream>>>(p);
    }
    { // a = quad(q @ k^T * 0.01) per batch
      GP p{};
      p.A = q; p.asb = 2097152;
      p.B[0] = kb; p.bsb = 2097152;
      p.O[0] = a; p.osb = 4194304;
      p.M = 2048; p.N = 2048; p.K = 1024; p.lda = 1024; p.ldb = 1024; p.ldo = 2048;
      p.alpha[0] = 0.01f; p.epi[0] = 2;
      gemmS_k<<<dim3(16, 16, 2), 256, SHS, stream>>>(p);
    }
    if (fused) {
      // x = (x + (a@u)*0.001)*0.05 ; h = x*ln2*0.1   (Wo folded into u)
      GP p{};
      p.A = a; p.asb = 0;
      p.B[0] = uT; p.bsb = 2097152; p.msel = 1;
      p.M = 4096; p.N = 1024; p.K = 2048; p.lda = 2048; p.ldb = 2048; p.ldo = 1024;
      p.alpha[0] = 0.001f; p.epi[0] = 3;
      p.xres = x; p.lnw = ln2w + (size_t)l * 1024; p.rscale = 0.05f; p.hout = h;
      gemmS_k<<<dim3(32, 8, 1), 256, SHS, stream>>>(p);
    } else {
      { // ao = a @ v * 0.01
        GP p{};
        p.A = a; p.asb = 0;
        p.B[0] = uT; p.bsb = 2097152; p.msel = 1;
        p.O[0] = ao; p.osb = 0;
        p.M = 4096; p.N = 1024; p.K = 2048; p.lda = 2048; p.ldb = 2048; p.ldo = 1024;
        p.alpha[0] = 0.01f; p.epi[0] = 0;
        gemmS_k<<<dim3(32, 8, 1), 256, SHS, stream>>>(p);
      }
      { // x = (x + ao@Wo^T*0.1)*0.05 ; h = x*ln2*0.1
        GP p{};
        p.A = ao; p.asb = 0; p.B[0] = lw + 3145728;
        p.M = 4096; p.N = 1024; p.K = 1024; p.lda = 1024; p.ldb = 1024; p.ldo = 1024;
        p.alpha[0] = 0.1f; p.epi[0] = 3;
        p.xres = x; p.lnw = ln2w + (size_t)l * 1024; p.rscale = 0.05f; p.hout = h;
        gemmS_k<<<dim3(32, 8, 1), 256, SHS, stream>>>(p);
      }
    }
    { // m = quad(h @ fc1^T * 0.05)
      GP p{};
      p.A = h; p.asb = 0;
      p.B[0] = fused ? (lw + 2097152) : (lw + 4194304);
      p.O[0] = mb;
      p.M = 4096; p.N = 2048; p.K = 1024; p.lda = 1024; p.ldb = 1024; p.ldo = 2048;
      p.alpha[0] = 0.05f; p.epi[0] = 2;
      gemmS_k<<<dim3(32, 16, 1), 256, SHS, stream>>>(p);
    }
    { // x = (x + m@fc2^T*0.05)*0.05*s ; h = x*ln_next*0.1
      GP p{};
      p.A = mb; p.asb = 0;
      p.B[0] = fused ? (lw + 4194304) : (lw + 6291456);
      p.M = 4096; p.N = 1024; p.K = 2048; p.lda = 2048; p.ldb = 2048; p.ldo = 1024;
      p.alpha[0] = 0.05f; p.epi[0] = 3;
      p.xres = x;
      p.rscale = (l < 11) ? 0.005f : 0.05f;
      p.lnw = (l < 11) ? (ln1w + (size_t)(l + 1) * 1024) : lnfw;
      p.hout = h;
      gemmS_k<<<dim3(32, 8, 1), 256, SHS, stream>>>(p);
    }
  }

  cvt_k<<<2048, 256, 0, stream>>>(lmh, lmhb, 32768000ll);
  { // logits = h @ lm_head^T * 0.5 (f32)
    GP p{};
    p.A = h; p.asb = 0; p.B[0] = lmhb;
    p.M = 4096; p.N = 32000; p.K = 1024; p.lda = 1024; p.ldb = 1024; p.ldo = 0;
    p.alpha[0] = 0.5f; p.epi[0] = 4;
    p.fout = out; p.ldf = 32000;
    gemmL_k<<<dim3(16, 125, 1), 512, SHL, stream>>>(p);
  }
}